// Round 1
// baseline (2621.183 us; speedup 1.0000x reference)
//
#include <hip/hip_runtime.h>

#define NEG_SLOPE 0.01f

__device__ __forceinline__ float lrelu(float x) { return x > 0.f ? x : NEG_SLOPE * x; }

// ---------------- degree counts ----------------
__global__ __launch_bounds__(256) void deg_kernel(const int* __restrict__ snd,
                                                  const int* __restrict__ rcv,
                                                  float* __restrict__ deg_s,
                                                  float* __restrict__ deg_r, int nE)
{
    int i = blockIdx.x * 256 + threadIdx.x;
    int stride = gridDim.x * 256;
    for (; i < nE; i += stride) {
        atomicAdd(&deg_s[snd[i]], 1.0f);
        atomicAdd(&deg_r[rcv[i]], 1.0f);
    }
}

// ---------------- fused MLP: h = lrelu(lrelu(X@W1+b1)@W2+b2) * rsqrt(max(deg_s,1)) ----------------
// 64 rows per block, 256 threads, 4x4 micro-tile per thread (16x16 thread grid over 64x64 tile)
__global__ __launch_bounds__(256) void mlp_kernel(
    const float* __restrict__ X, const float* __restrict__ W1, const float* __restrict__ b1,
    const float* __restrict__ W2, const float* __restrict__ b2,
    const float* __restrict__ deg_s, float* __restrict__ out, int nN)
{
    __shared__ float W2s[64 * 64];     // 16 KB
    __shared__ float Wc[16 * 64];      // 4 KB  (W1 chunk, staged per kc)
    __shared__ float Xs[16][68];       // 4.35 KB (X^T chunk, padded)
    __shared__ float H1s[64][68];      // 17.4 KB (h1 transposed [col][row], padded)

    const int t  = threadIdx.x;
    const int tx = t & 15;             // col group (4 cols each)
    const int ty = t >> 4;             // row group (4 rows each)
    const int row0 = blockIdx.x * 64;

    // stage W2 fully
    for (int i = t; i < 1024; i += 256)
        ((float4*)W2s)[i] = ((const float4*)W2)[i];

    const float4 bias1 = *(const float4*)&b1[4 * tx];
    const float4 bias2 = *(const float4*)&b2[4 * tx];

    float acc[4][4];
#pragma unroll
    for (int i = 0; i < 4; ++i)
#pragma unroll
        for (int j = 0; j < 4; ++j) acc[i][j] = 0.f;

    const int r  = t >> 2;             // 0..63 (row for staging)
    const int kq = (t & 3) * 4;        // 0,4,8,12 (k for staging)
    const int grow_ld = row0 + r;

    for (int kc = 0; kc < 8; ++kc) {
        float4 v = make_float4(0.f, 0.f, 0.f, 0.f);
        if (grow_ld < nN) v = *(const float4*)&X[(size_t)grow_ld * 128 + kc * 16 + kq];
        float4 w4 = ((const float4*)(W1 + kc * 1024))[t];
        __syncthreads();
        Xs[kq + 0][r] = v.x; Xs[kq + 1][r] = v.y; Xs[kq + 2][r] = v.z; Xs[kq + 3][r] = v.w;
        ((float4*)Wc)[t] = w4;
        __syncthreads();
#pragma unroll
        for (int k = 0; k < 16; ++k) {
            const float4 a = *(const float4*)&Xs[k][4 * ty];
            const float4 b = *(const float4*)&Wc[k * 64 + 4 * tx];
            acc[0][0] += a.x * b.x; acc[0][1] += a.x * b.y; acc[0][2] += a.x * b.z; acc[0][3] += a.x * b.w;
            acc[1][0] += a.y * b.x; acc[1][1] += a.y * b.y; acc[1][2] += a.y * b.z; acc[1][3] += a.y * b.w;
            acc[2][0] += a.z * b.x; acc[2][1] += a.z * b.y; acc[2][2] += a.z * b.z; acc[2][3] += a.z * b.w;
            acc[3][0] += a.w * b.x; acc[3][1] += a.w * b.y; acc[3][2] += a.w * b.z; acc[3][3] += a.w * b.w;
        }
    }

    // bias + leaky, store h1 transposed [col][row]
    __syncthreads();
#pragma unroll
    for (int i = 0; i < 4; ++i) {
        float h0 = lrelu(acc[i][0] + bias1.x);
        float h1 = lrelu(acc[i][1] + bias1.y);
        float h2 = lrelu(acc[i][2] + bias1.z);
        float h3 = lrelu(acc[i][3] + bias1.w);
        H1s[4 * tx + 0][4 * ty + i] = h0;
        H1s[4 * tx + 1][4 * ty + i] = h1;
        H1s[4 * tx + 2][4 * ty + i] = h2;
        H1s[4 * tx + 3][4 * ty + i] = h3;
    }
    __syncthreads();

    // layer 2: 64x64 @ 64x64
#pragma unroll
    for (int i = 0; i < 4; ++i)
#pragma unroll
        for (int j = 0; j < 4; ++j) acc[i][j] = 0.f;

#pragma unroll 4
    for (int k = 0; k < 64; ++k) {
        const float4 a = *(const float4*)&H1s[k][4 * ty];
        const float4 b = *(const float4*)&W2s[k * 64 + 4 * tx];
        acc[0][0] += a.x * b.x; acc[0][1] += a.x * b.y; acc[0][2] += a.x * b.z; acc[0][3] += a.x * b.w;
        acc[1][0] += a.y * b.x; acc[1][1] += a.y * b.y; acc[1][2] += a.y * b.z; acc[1][3] += a.y * b.w;
        acc[2][0] += a.z * b.x; acc[2][1] += a.z * b.y; acc[2][2] += a.z * b.z; acc[2][3] += a.z * b.w;
        acc[3][0] += a.w * b.x; acc[3][1] += a.w * b.y; acc[3][2] += a.w * b.z; acc[3][3] += a.w * b.w;
    }

#pragma unroll
    for (int i = 0; i < 4; ++i) {
        int grow = row0 + 4 * ty + i;
        if (grow < nN) {
            float rs = rsqrtf(fmaxf(deg_s[grow], 1.0f));
            float4 o;
            o.x = lrelu(acc[i][0] + bias2.x) * rs;
            o.y = lrelu(acc[i][1] + bias2.y) * rs;
            o.z = lrelu(acc[i][2] + bias2.z) * rs;
            o.w = lrelu(acc[i][3] + bias2.w) * rs;
            *(float4*)&out[(size_t)grow * 64 + 4 * tx] = o;
        }
    }
}

// ---------------- edge aggregation: out[rcv] += x[snd], F = CH*4 features ----------------
template <int CH>
__global__ __launch_bounds__(256) void agg_kernel(const float* __restrict__ x,
                                                  const int* __restrict__ snd,
                                                  const int* __restrict__ rcv,
                                                  float* __restrict__ out, int nE)
{
    int i = blockIdx.x * 256 + threadIdx.x;
    const int total = nE * CH;
    const int stride = gridDim.x * 256;
    for (; i < total; i += stride) {
        const int e = i / CH;
        const int c = i - e * CH;
        const int s = snd[e];
        const int d = rcv[e];
        const float4 v = *(const float4*)&x[(size_t)s * (CH * 4) + c * 4];
        float* o = &out[(size_t)d * (CH * 4) + c * 4];
        atomicAdd(o + 0, v.x);
        atomicAdd(o + 1, v.y);
        atomicAdd(o + 2, v.z);
        atomicAdd(o + 3, v.w);
    }
}

// ---------------- head: y = ((x*rsqrt(deg_r)) @ W3 + b3) * rsqrt(deg_s) ----------------
__global__ __launch_bounds__(256) void head_kernel(
    const float* __restrict__ xin, const float* __restrict__ W3, const float* __restrict__ b3,
    const float* __restrict__ deg_s, const float* __restrict__ deg_r,
    float* __restrict__ out, int nN)
{
    __shared__ float W3s[64 * 40];
    __shared__ float b3s[40];
    const int t = threadIdx.x;
    for (int i = t; i < 640; i += 256)
        ((float4*)W3s)[i] = ((const float4*)W3)[i];
    if (t < 40) b3s[t] = b3[t];
    __syncthreads();

    const int row = blockIdx.x * 256 + t;
    if (row >= nN) return;
    const float rin  = rsqrtf(fmaxf(deg_r[row], 1.f));
    const float rout = rsqrtf(fmaxf(deg_s[row], 1.f));

    float acc[40];
#pragma unroll
    for (int c = 0; c < 40; ++c) acc[c] = 0.f;

    const float* xr = &xin[(size_t)row * 64];
    for (int k4 = 0; k4 < 16; ++k4) {
        float4 xv = *(const float4*)&xr[k4 * 4];
        xv.x *= rin; xv.y *= rin; xv.z *= rin; xv.w *= rin;
        const float xk[4] = {xv.x, xv.y, xv.z, xv.w};
#pragma unroll
        for (int kk = 0; kk < 4; ++kk) {
            const float* wrow = &W3s[(k4 * 4 + kk) * 40];
#pragma unroll
            for (int c = 0; c < 40; ++c) acc[c] += xk[kk] * wrow[c];
        }
    }

    float* orow = &out[(size_t)row * 40];
#pragma unroll
    for (int c4 = 0; c4 < 10; ++c4) {
        float4 o;
        o.x = (acc[c4 * 4 + 0] + b3s[c4 * 4 + 0]) * rout;
        o.y = (acc[c4 * 4 + 1] + b3s[c4 * 4 + 1]) * rout;
        o.z = (acc[c4 * 4 + 2] + b3s[c4 * 4 + 2]) * rout;
        o.w = (acc[c4 * 4 + 3] + b3s[c4 * 4 + 3]) * rout;
        *(float4*)&orow[c4 * 4] = o;
    }
}

// ---------------- final: scale by rsqrt(deg_r) + softmax ----------------
__global__ __launch_bounds__(256) void softmax_kernel(const float* __restrict__ acc,
                                                      const float* __restrict__ deg_r,
                                                      float* __restrict__ out, int nN)
{
    const int row = blockIdx.x * 256 + threadIdx.x;
    if (row >= nN) return;
    const float rs = rsqrtf(fmaxf(deg_r[row], 1.f));
    float v[40];
    const float* ar = &acc[(size_t)row * 40];
#pragma unroll
    for (int c4 = 0; c4 < 10; ++c4) {
        float4 x = *(const float4*)&ar[c4 * 4];
        v[c4 * 4 + 0] = x.x * rs;
        v[c4 * 4 + 1] = x.y * rs;
        v[c4 * 4 + 2] = x.z * rs;
        v[c4 * 4 + 3] = x.w * rs;
    }
    float m = v[0];
#pragma unroll
    for (int c = 1; c < 40; ++c) m = fmaxf(m, v[c]);
    float s = 0.f;
#pragma unroll
    for (int c = 0; c < 40; ++c) { v[c] = __expf(v[c] - m); s += v[c]; }
    const float inv = 1.f / s;
    float* orow = &out[(size_t)row * 40];
#pragma unroll
    for (int c4 = 0; c4 < 10; ++c4) {
        float4 o;
        o.x = v[c4 * 4 + 0] * inv;
        o.y = v[c4 * 4 + 1] * inv;
        o.z = v[c4 * 4 + 2] * inv;
        o.w = v[c4 * 4 + 3] * inv;
        *(float4*)&orow[c4 * 4] = o;
    }
}

extern "C" void kernel_launch(void* const* d_in, const int* in_sizes, int n_in,
                              void* d_out, int out_size, void* d_ws, size_t ws_size,
                              hipStream_t stream)
{
    const float* nodes = (const float*)d_in[0];
    const int*   snd   = (const int*)d_in[1];
    const int*   rcv   = (const int*)d_in[2];
    const float* W1    = (const float*)d_in[3];
    const float* b1    = (const float*)d_in[4];
    const float* W2    = (const float*)d_in[5];
    const float* b2    = (const float*)d_in[6];
    const float* W3    = (const float*)d_in[7];
    const float* b3    = (const float*)d_in[8];

    const int nN = in_sizes[0] / 128;
    const int nE = in_sizes[1];

    float* ws    = (float*)d_ws;
    float* deg_s = ws;
    float* deg_r = ws + nN;
    float* bufA  = ws + 2 * (size_t)nN;          // N*64 (h2 scaled), later N*40 (y scaled)
    float* bufB  = bufA + (size_t)nN * 64;       // N*64 (agg1), later N*40 (agg2)

    hipMemsetAsync(deg_s, 0, sizeof(float) * 2 * (size_t)nN, stream);
    hipMemsetAsync(bufB, 0, sizeof(float) * (size_t)nN * 64, stream);

    deg_kernel<<<2048, 256, 0, stream>>>(snd, rcv, deg_s, deg_r, nE);
    mlp_kernel<<<(nN + 63) / 64, 256, 0, stream>>>(nodes, W1, b1, W2, b2, deg_s, bufA, nN);
    agg_kernel<16><<<4096, 256, 0, stream>>>(bufA, snd, rcv, bufB, nE);
    head_kernel<<<(nN + 255) / 256, 256, 0, stream>>>(bufB, W3, b3, deg_s, deg_r, bufA, nN);
    hipMemsetAsync(bufB, 0, sizeof(float) * (size_t)nN * 40, stream);
    agg_kernel<10><<<4096, 256, 0, stream>>>(bufA, snd, rcv, bufB, nE);
    softmax_kernel<<<(nN + 255) / 256, 256, 0, stream>>>(bufB, deg_r, (float*)d_out, nN);
}

// Round 2
// 456.689 us; speedup vs baseline: 5.7395x; 5.7395x over previous
//
#include <hip/hip_runtime.h>

#define NEG_SLOPE 0.01f

__device__ __forceinline__ float lrelu(float x) { return x > 0.f ? x : NEG_SLOPE * x; }
__device__ __forceinline__ float4 add4(float4 a, float4 b) {
    return make_float4(a.x + b.x, a.y + b.y, a.z + b.z, a.w + b.w);
}
__device__ __forceinline__ float4 mul4(float4 a, float s) {
    return make_float4(a.x * s, a.y * s, a.z * s, a.w * s);
}
__device__ __forceinline__ float4 fma4(float4 a, float s, float4 b) {
    return make_float4(a.x + s * b.x, a.y + s * b.y, a.z + s * b.z, a.w + s * b.w);
}

// ---------------- integer degree histogram ----------------
__global__ __launch_bounds__(256) void deg_kernel(const int* __restrict__ snd,
                                                  const int* __restrict__ rcv,
                                                  int* __restrict__ ds_i,
                                                  int* __restrict__ dr_i, int nE)
{
    int i = blockIdx.x * 256 + threadIdx.x;
    int stride = gridDim.x * 256;
    for (; i < nE; i += stride) {
        atomicAdd(&ds_i[snd[i]], 1);
        atomicAdd(&dr_i[rcv[i]], 1);
    }
}

// ---------------- scan stage 1: per-block (1024 elems) exclusive scan ----------------
__global__ __launch_bounds__(256) void scan1_kernel(const int* __restrict__ cnt,
                                                    int* __restrict__ rowptr,
                                                    int* __restrict__ bsums, int n)
{
    __shared__ int sd[256];
    const int t = threadIdx.x;
    const int base = blockIdx.x * 1024 + t * 4;
    int v0 = (base + 0 < n) ? cnt[base + 0] : 0;
    int v1 = (base + 1 < n) ? cnt[base + 1] : 0;
    int v2 = (base + 2 < n) ? cnt[base + 2] : 0;
    int v3 = (base + 3 < n) ? cnt[base + 3] : 0;
    const int p1 = v0, p2 = v0 + v1, p3 = v0 + v1 + v2;
    const int tot = p3 + v3;
    sd[t] = tot;
    __syncthreads();
    for (int off = 1; off < 256; off <<= 1) {
        int y = (t >= off) ? sd[t - off] : 0;
        __syncthreads();
        sd[t] += y;
        __syncthreads();
    }
    const int excl = sd[t] - tot;   // exclusive prefix of this thread within block
    if (base + 0 < n) rowptr[base + 0] = excl;
    if (base + 1 < n) rowptr[base + 1] = excl + p1;
    if (base + 2 < n) rowptr[base + 2] = excl + p2;
    if (base + 3 < n) rowptr[base + 3] = excl + p3;
    if (t == 255) bsums[blockIdx.x] = sd[255];
}

// ---------------- scan stage 2: scan block sums (nb <= 256) ----------------
__global__ __launch_bounds__(256) void scan2_kernel(int* __restrict__ bsums, int nb)
{
    __shared__ int sd[256];
    const int t = threadIdx.x;
    const int v = (t < nb) ? bsums[t] : 0;
    sd[t] = v;
    __syncthreads();
    for (int off = 1; off < 256; off <<= 1) {
        int y = (t >= off) ? sd[t - off] : 0;
        __syncthreads();
        sd[t] += y;
        __syncthreads();
    }
    if (t < nb) bsums[t] = sd[t] - v;   // exclusive
}

// ---------------- scan stage 3: add block offsets + compute rin/rout ----------------
__global__ __launch_bounds__(256) void scan3_kernel(int* __restrict__ rowptr,
                                                    const int* __restrict__ bsums,
                                                    const int* __restrict__ ds_i,
                                                    const int* __restrict__ dr_i,
                                                    float* __restrict__ rin,
                                                    float* __restrict__ rout,
                                                    int n, int nE)
{
    const int gid = blockIdx.x * 256 + threadIdx.x;
    if (gid < n) {
        rowptr[gid] += bsums[gid >> 10];
        rin[gid]  = rsqrtf(fmaxf((float)ds_i[gid], 1.f));
        rout[gid] = rsqrtf(fmaxf((float)dr_i[gid], 1.f));
    }
    if (gid == 0) rowptr[n] = nE;
}

// ---------------- CSR fill: scatter sender ids into receiver buckets ----------------
__global__ __launch_bounds__(256) void fill_kernel(const int* __restrict__ snd,
                                                   const int* __restrict__ rcv,
                                                   const int* __restrict__ rowptr,
                                                   int* __restrict__ cursor,
                                                   int* __restrict__ csr_src, int nE)
{
    int i = blockIdx.x * 256 + threadIdx.x;
    int stride = gridDim.x * 256;
    for (; i < nE; i += stride) {
        const int r = rcv[i];
        const int pos = atomicAdd(&cursor[r], 1);
        csr_src[rowptr[r] + pos] = snd[i];
    }
}

// ---------------- fused MLP + W3 projection:
// p = rin * ( lrelu(lrelu(X@W1+b1)@W2+b2) @ W3 )   [N,40]
__global__ __launch_bounds__(256) void mlp_kernel(
    const float* __restrict__ X, const float* __restrict__ W1, const float* __restrict__ b1,
    const float* __restrict__ W2, const float* __restrict__ b2, const float* __restrict__ W3,
    const float* __restrict__ rin, float* __restrict__ p, int nN)
{
    __shared__ float W2s[64 * 64];     // 16 KB (reused for W3 in epilogue)
    __shared__ float Wc[16 * 64];      // 4 KB  (W1 chunk, staged per kc)
    __shared__ float Xs[16][68];       // X^T chunk, padded
    __shared__ float H1s[64][68];      // h1 transposed [col][row]; later h2 [row][col]

    const int t  = threadIdx.x;
    const int tx = t & 15;             // col group (4 cols each)
    const int ty = t >> 4;             // row group (4 rows each)
    const int row0 = blockIdx.x * 64;

    // stage W2 fully
    for (int i = t; i < 1024; i += 256)
        ((float4*)W2s)[i] = ((const float4*)W2)[i];

    const float4 bias1 = *(const float4*)&b1[4 * tx];
    const float4 bias2 = *(const float4*)&b2[4 * tx];

    float acc[4][4];
#pragma unroll
    for (int i = 0; i < 4; ++i)
#pragma unroll
        for (int j = 0; j < 4; ++j) acc[i][j] = 0.f;

    const int r  = t >> 2;             // 0..63 (row for staging)
    const int kq = (t & 3) * 4;        // 0,4,8,12 (k for staging)
    const int grow_ld = row0 + r;

    for (int kc = 0; kc < 8; ++kc) {
        float4 v = make_float4(0.f, 0.f, 0.f, 0.f);
        if (grow_ld < nN) v = *(const float4*)&X[(size_t)grow_ld * 128 + kc * 16 + kq];
        float4 w4 = ((const float4*)(W1 + kc * 1024))[t];
        __syncthreads();
        Xs[kq + 0][r] = v.x; Xs[kq + 1][r] = v.y; Xs[kq + 2][r] = v.z; Xs[kq + 3][r] = v.w;
        ((float4*)Wc)[t] = w4;
        __syncthreads();
#pragma unroll
        for (int k = 0; k < 16; ++k) {
            const float4 a = *(const float4*)&Xs[k][4 * ty];
            const float4 b = *(const float4*)&Wc[k * 64 + 4 * tx];
            acc[0][0] += a.x * b.x; acc[0][1] += a.x * b.y; acc[0][2] += a.x * b.z; acc[0][3] += a.x * b.w;
            acc[1][0] += a.y * b.x; acc[1][1] += a.y * b.y; acc[1][2] += a.y * b.z; acc[1][3] += a.y * b.w;
            acc[2][0] += a.z * b.x; acc[2][1] += a.z * b.y; acc[2][2] += a.z * b.z; acc[2][3] += a.z * b.w;
            acc[3][0] += a.w * b.x; acc[3][1] += a.w * b.y; acc[3][2] += a.w * b.z; acc[3][3] += a.w * b.w;
        }
    }

    // bias + leaky, store h1 transposed [col][row]
    __syncthreads();
#pragma unroll
    for (int i = 0; i < 4; ++i) {
        float h0 = lrelu(acc[i][0] + bias1.x);
        float h1 = lrelu(acc[i][1] + bias1.y);
        float h2 = lrelu(acc[i][2] + bias1.z);
        float h3 = lrelu(acc[i][3] + bias1.w);
        H1s[4 * tx + 0][4 * ty + i] = h0;
        H1s[4 * tx + 1][4 * ty + i] = h1;
        H1s[4 * tx + 2][4 * ty + i] = h2;
        H1s[4 * tx + 3][4 * ty + i] = h3;
    }
    __syncthreads();

    // layer 2: 64x64 @ 64x64
#pragma unroll
    for (int i = 0; i < 4; ++i)
#pragma unroll
        for (int j = 0; j < 4; ++j) acc[i][j] = 0.f;

#pragma unroll 4
    for (int k = 0; k < 64; ++k) {
        const float4 a = *(const float4*)&H1s[k][4 * ty];
        const float4 b = *(const float4*)&W2s[k * 64 + 4 * tx];
        acc[0][0] += a.x * b.x; acc[0][1] += a.x * b.y; acc[0][2] += a.x * b.z; acc[0][3] += a.x * b.w;
        acc[1][0] += a.y * b.x; acc[1][1] += a.y * b.y; acc[1][2] += a.y * b.z; acc[1][3] += a.y * b.w;
        acc[2][0] += a.z * b.x; acc[2][1] += a.z * b.y; acc[2][2] += a.z * b.z; acc[2][3] += a.z * b.w;
        acc[3][0] += a.w * b.x; acc[3][1] += a.w * b.y; acc[3][2] += a.w * b.z; acc[3][3] += a.w * b.w;
    }

    // h2 (bias+lrelu) -> LDS [row][col]; stage W3 into W2s space
    __syncthreads();
#pragma unroll
    for (int i = 0; i < 4; ++i) {
        H1s[4 * ty + i][4 * tx + 0] = lrelu(acc[i][0] + bias2.x);
        H1s[4 * ty + i][4 * tx + 1] = lrelu(acc[i][1] + bias2.y);
        H1s[4 * ty + i][4 * tx + 2] = lrelu(acc[i][2] + bias2.z);
        H1s[4 * ty + i][4 * tx + 3] = lrelu(acc[i][3] + bias2.w);
    }
    for (int idx = t; idx < 640; idx += 256)
        ((float4*)W2s)[idx] = ((const float4*)W3)[idx];
    __syncthreads();

    // projection: each thread computes one row's 10-col slice of h2 @ W3
    const int row  = t >> 2;           // 0..63
    const int cseg = t & 3;            // 10-col segment
    float a10[10];
#pragma unroll
    for (int j = 0; j < 10; ++j) a10[j] = 0.f;
    for (int k = 0; k < 64; ++k) {
        const float a = H1s[row][k];
        const float* w = &W2s[k * 40 + cseg * 10];
#pragma unroll
        for (int j = 0; j < 10; ++j) a10[j] += a * w[j];
    }
    const int grow = row0 + row;
    if (grow < nN) {
        const float rs = rin[grow];
        float* pr = &p[(size_t)grow * 40 + cseg * 10];
#pragma unroll
        for (int m = 0; m < 5; ++m) {
            float2 st = make_float2(a10[2 * m] * rs, a10[2 * m + 1] * rs);
            ((float2*)pr)[m] = st;
        }
    }
}

// ---------------- agg1 (CSR gather): q = rin*rout * sum_{src} p[src]; c = rout * sum rin[src]
__global__ __launch_bounds__(256) void agg1_kernel(const float* __restrict__ p,
                                                   const int* __restrict__ csr_src,
                                                   const int* __restrict__ rowptr,
                                                   const float* __restrict__ rin,
                                                   const float* __restrict__ rout,
                                                   float* __restrict__ qbuf,
                                                   float* __restrict__ cbuf, int nN)
{
    const int gid = blockIdx.x * 256 + threadIdx.x;
    const int node = gid >> 2;
    const int q4 = gid & 3;
    if (node >= nN) return;
    const int beg = rowptr[node], end = rowptr[node + 1];
    const int jb0 = q4, jb1 = 4 + q4, jb2 = 8 + q4;
    const bool has2 = (q4 < 2);
    float4 a0 = make_float4(0, 0, 0, 0), a1 = a0, a2 = a0;
    float cs = 0.f;
    for (int e = beg; e < end; ++e) {
        const int src = csr_src[e];
        const float4* px = (const float4*)(p + (size_t)src * 40);
        a0 = add4(a0, px[jb0]);
        a1 = add4(a1, px[jb1]);
        if (has2) a2 = add4(a2, px[jb2]);
        if (q4 == 0) cs += rin[src];
    }
    const float sc = rin[node] * rout[node];
    float4* qr = (float4*)(qbuf + (size_t)node * 40);
    qr[jb0] = mul4(a0, sc);
    qr[jb1] = mul4(a1, sc);
    if (has2) qr[jb2] = mul4(a2, sc);
    if (q4 == 0) cbuf[node] = cs * rout[node];
}

// ---------------- agg2 + bias-term + softmax -> out ----------------
__global__ __launch_bounds__(256) void agg2_kernel(const float* __restrict__ qbuf,
                                                   const int* __restrict__ csr_src,
                                                   const int* __restrict__ rowptr,
                                                   const float* __restrict__ rout,
                                                   const float* __restrict__ cbuf,
                                                   const float* __restrict__ b3,
                                                   float* __restrict__ out, int nN)
{
    const int gid = blockIdx.x * 256 + threadIdx.x;
    const int node = gid >> 2;
    const int q4 = gid & 3;
    if (node >= nN) return;
    const int beg = rowptr[node], end = rowptr[node + 1];
    const int jb0 = q4, jb1 = 4 + q4, jb2 = 8 + q4;
    const bool has2 = (q4 < 2);
    float4 a0 = make_float4(0, 0, 0, 0), a1 = a0, a2 = a0;
    for (int e = beg; e < end; ++e) {
        const int src = csr_src[e];
        const float4* px = (const float4*)(qbuf + (size_t)src * 40);
        a0 = add4(a0, px[jb0]);
        a1 = add4(a1, px[jb1]);
        if (has2) a2 = add4(a2, px[jb2]);
    }
    const float ro = rout[node];
    const float c  = cbuf[node];
    const float4 b0 = ((const float4*)b3)[jb0];
    const float4 b1 = ((const float4*)b3)[jb1];
    float4 z0 = fma4(mul4(a0, ro), c, b0);
    float4 z1 = fma4(mul4(a1, ro), c, b1);
    float4 z2 = make_float4(0, 0, 0, 0);
    if (has2) {
        const float4 b2v = ((const float4*)b3)[jb2];
        z2 = fma4(mul4(a2, ro), c, b2v);
    }
    // group (4-lane) max
    float m = fmaxf(fmaxf(z0.x, z0.y), fmaxf(z0.z, z0.w));
    m = fmaxf(m, fmaxf(fmaxf(z1.x, z1.y), fmaxf(z1.z, z1.w)));
    if (has2) m = fmaxf(m, fmaxf(fmaxf(z2.x, z2.y), fmaxf(z2.z, z2.w)));
    m = fmaxf(m, __shfl_xor(m, 1));
    m = fmaxf(m, __shfl_xor(m, 2));
    // exp + group sum
    z0.x = __expf(z0.x - m); z0.y = __expf(z0.y - m); z0.z = __expf(z0.z - m); z0.w = __expf(z0.w - m);
    z1.x = __expf(z1.x - m); z1.y = __expf(z1.y - m); z1.z = __expf(z1.z - m); z1.w = __expf(z1.w - m);
    float s = z0.x + z0.y + z0.z + z0.w + z1.x + z1.y + z1.z + z1.w;
    if (has2) {
        z2.x = __expf(z2.x - m); z2.y = __expf(z2.y - m); z2.z = __expf(z2.z - m); z2.w = __expf(z2.w - m);
        s += z2.x + z2.y + z2.z + z2.w;
    }
    s += __shfl_xor(s, 1);
    s += __shfl_xor(s, 2);
    const float inv = 1.f / s;
    float4* orow = (float4*)(out + (size_t)node * 40);
    orow[jb0] = mul4(z0, inv);
    orow[jb1] = mul4(z1, inv);
    if (has2) orow[jb2] = mul4(z2, inv);
}

extern "C" void kernel_launch(void* const* d_in, const int* in_sizes, int n_in,
                              void* d_out, int out_size, void* d_ws, size_t ws_size,
                              hipStream_t stream)
{
    const float* nodes = (const float*)d_in[0];
    const int*   snd   = (const int*)d_in[1];
    const int*   rcv   = (const int*)d_in[2];
    const float* W1    = (const float*)d_in[3];
    const float* b1    = (const float*)d_in[4];
    const float* W2    = (const float*)d_in[5];
    const float* b2    = (const float*)d_in[6];
    const float* W3    = (const float*)d_in[7];
    const float* b3    = (const float*)d_in[8];

    const int nN = in_sizes[0] / 128;
    const int nE = in_sizes[1];

    // workspace layout (element offsets, 16B-aligned chunks)
    size_t off = 0;
    auto alloc = [&](size_t n) { size_t r = off; off += (n + 3) & ~(size_t)3; return r; };
    int*   ds_i    = (int*)d_ws + alloc(nN);
    int*   dr_i    = (int*)d_ws + alloc(nN);
    int*   cursor  = (int*)d_ws + alloc(nN);
    int*   rowptr  = (int*)d_ws + alloc(nN + 1);
    int*   bsums   = (int*)d_ws + alloc(256);
    float* rin     = (float*)d_ws + alloc(nN);
    float* rout    = (float*)d_ws + alloc(nN);
    float* cbuf    = (float*)d_ws + alloc(nN);
    int*   csr_src = (int*)d_ws + alloc(nE);
    float* pbuf    = (float*)d_ws + alloc((size_t)nN * 40);
    float* qbuf    = (float*)d_ws + alloc((size_t)nN * 40);

    // zero the three histogram/cursor arrays (contiguous)
    hipMemsetAsync(ds_i, 0, sizeof(int) * 3 * (size_t)((nN + 3) & ~3), stream);

    const int nb1 = (nN + 1023) / 1024;   // 98 for N=100000 (<=256 required)

    deg_kernel<<<2048, 256, 0, stream>>>(snd, rcv, ds_i, dr_i, nE);
    scan1_kernel<<<nb1, 256, 0, stream>>>(dr_i, rowptr, bsums, nN);
    scan2_kernel<<<1, 256, 0, stream>>>(bsums, nb1);
    scan3_kernel<<<(nN + 255) / 256, 256, 0, stream>>>(rowptr, bsums, ds_i, dr_i, rin, rout, nN, nE);
    fill_kernel<<<2048, 256, 0, stream>>>(snd, rcv, rowptr, cursor, csr_src, nE);
    mlp_kernel<<<(nN + 63) / 64, 256, 0, stream>>>(nodes, W1, b1, W2, b2, W3, rin, pbuf, nN);
    agg1_kernel<<<((size_t)nN * 4 + 255) / 256, 256, 0, stream>>>(pbuf, csr_src, rowptr, rin, rout, qbuf, cbuf, nN);
    agg2_kernel<<<((size_t)nN * 4 + 255) / 256, 256, 0, stream>>>(qbuf, csr_src, rowptr, rout, cbuf, b3, (float*)d_out, nN);
}

// Round 3
// 292.103 us; speedup vs baseline: 8.9735x; 1.5634x over previous
//
#include <hip/hip_runtime.h>

#define NEG_SLOPE 0.01f
#define RANGE_BITS 14
#define RANGE (1 << RANGE_BITS)     // 16384 nodes per histogram range (64 KB LDS)
#define SLICE_BITS 16
#define SLICE (1 << SLICE_BITS)     // 65536 edges per slice

__device__ __forceinline__ float lrelu(float x) { return x > 0.f ? x : NEG_SLOPE * x; }
__device__ __forceinline__ float4 add4(float4 a, float4 b) {
    return make_float4(a.x + b.x, a.y + b.y, a.z + b.z, a.w + b.w);
}
__device__ __forceinline__ float4 mul4(float4 a, float s) {
    return make_float4(a.x * s, a.y * s, a.z * s, a.w * s);
}
__device__ __forceinline__ float4 fma4(float4 a, float s, float4 b) {
    return make_float4(a.x + s * b.x, a.y + s * b.y, a.z + s * b.z, a.w + s * b.w);
}

// ---------------- pass A: per-(array,range,slice) LDS histogram ----------------
// a=0: rcv (also records per-edge local position); a=1: snd (counts only)
__global__ __launch_bounds__(1024) void count_kernel(
    const int* __restrict__ snd, const int* __restrict__ rcv,
    int* __restrict__ partial, int* __restrict__ pos_local,
    int nE, int NR, int NS)
{
    __shared__ int hist[RANGE];
    const int b = blockIdx.x;
    const int a = b / (NR * NS);
    const int rem = b - a * NR * NS;
    const int r = rem / NS;
    const int s = rem - r * NS;
    const int t = threadIdx.x;
    for (int k = t; k < RANGE; k += 1024) hist[k] = 0;
    __syncthreads();
    const int base = r << RANGE_BITS;
    const int lo = s << SLICE_BITS;
    const int hi = min(lo + SLICE, nE);
    if (a == 0) {
        for (int i = lo + t; i < hi; i += 1024) {
            const int v = rcv[i];
            const unsigned d = (unsigned)(v - base);
            if (d < (unsigned)RANGE) {
                const int lp = atomicAdd(&hist[d], 1);
                pos_local[i] = lp;
            }
        }
    } else {
        for (int i = lo + t; i < hi; i += 1024) {
            const int v = snd[i];
            const unsigned d = (unsigned)(v - base);
            if (d < (unsigned)RANGE) atomicAdd(&hist[d], 1);
        }
    }
    __syncthreads();
    int* dst = partial + (size_t)((a * NR + r) * NS + s) * RANGE;
    for (int k = t; k < RANGE; k += 1024) dst[k] = hist[k];
}

// ---------------- pass B: scan rcv partials over slices (in place), degrees, rin/rout ----------------
__global__ __launch_bounds__(256) void scanp_kernel(
    int* __restrict__ partial,
    int* __restrict__ dr_i,
    float* __restrict__ rin, float* __restrict__ rout,
    int nN, int NR, int NS)
{
    const int gid = blockIdx.x * 256 + threadIdx.x;
    if (gid >= (NR << RANGE_BITS)) return;
    const int r = gid >> RANGE_BITS;
    const int node = gid & (RANGE - 1);
    int* prcv = partial + (size_t)(r * NS) * RANGE + node;
    int run = 0;
    for (int s = 0; s < NS; ++s) {
        int* p = prcv + (size_t)s * RANGE;
        const int c = *p;
        *p = run;
        run += c;
    }
    const int* psnd = partial + (size_t)((NR + r) * NS) * RANGE + node;
    int tot = 0;
    for (int s = 0; s < NS; ++s) tot += psnd[(size_t)s * RANGE];
    if (gid < nN) {
        dr_i[gid] = run;
        rout[gid] = rsqrtf(fmaxf((float)run, 1.f));
        rin[gid]  = rsqrtf(fmaxf((float)tot, 1.f));
    }
}

// ---------------- scan stage 1: per-block (1024 elems) exclusive scan ----------------
__global__ __launch_bounds__(256) void scan1_kernel(const int* __restrict__ cnt,
                                                    int* __restrict__ rowptr,
                                                    int* __restrict__ bsums, int n)
{
    __shared__ int sd[256];
    const int t = threadIdx.x;
    const int base = blockIdx.x * 1024 + t * 4;
    int v0 = (base + 0 < n) ? cnt[base + 0] : 0;
    int v1 = (base + 1 < n) ? cnt[base + 1] : 0;
    int v2 = (base + 2 < n) ? cnt[base + 2] : 0;
    int v3 = (base + 3 < n) ? cnt[base + 3] : 0;
    const int p1 = v0, p2 = v0 + v1, p3 = v0 + v1 + v2;
    const int tot = p3 + v3;
    sd[t] = tot;
    __syncthreads();
    for (int off = 1; off < 256; off <<= 1) {
        int y = (t >= off) ? sd[t - off] : 0;
        __syncthreads();
        sd[t] += y;
        __syncthreads();
    }
    const int excl = sd[t] - tot;
    if (base + 0 < n) rowptr[base + 0] = excl;
    if (base + 1 < n) rowptr[base + 1] = excl + p1;
    if (base + 2 < n) rowptr[base + 2] = excl + p2;
    if (base + 3 < n) rowptr[base + 3] = excl + p3;
    if (t == 255) bsums[blockIdx.x] = sd[255];
}

// ---------------- scan stage 2: scan block sums (nb <= 256) ----------------
__global__ __launch_bounds__(256) void scan2_kernel(int* __restrict__ bsums, int nb)
{
    __shared__ int sd[256];
    const int t = threadIdx.x;
    const int v = (t < nb) ? bsums[t] : 0;
    sd[t] = v;
    __syncthreads();
    for (int off = 1; off < 256; off <<= 1) {
        int y = (t >= off) ? sd[t - off] : 0;
        __syncthreads();
        sd[t] += y;
        __syncthreads();
    }
    if (t < nb) bsums[t] = sd[t] - v;
}

// ---------------- scan stage 3: add block offsets ----------------
__global__ __launch_bounds__(256) void scan3_kernel(int* __restrict__ rowptr,
                                                    const int* __restrict__ bsums,
                                                    int n, int nE)
{
    const int gid = blockIdx.x * 256 + threadIdx.x;
    if (gid < n) rowptr[gid] += bsums[gid >> 10];
    if (gid == 0) rowptr[n] = nE;
}

// ---------------- pass C: atomic-free CSR fill ----------------
__global__ __launch_bounds__(256) void fill_kernel(
    const int* __restrict__ snd, const int* __restrict__ rcv,
    const int* __restrict__ pos_local, const int* __restrict__ partial,
    const int* __restrict__ rowptr, int* __restrict__ csr_src,
    int nE, int NS)
{
    const int i = blockIdx.x * 256 + threadIdx.x;
    if (i >= nE) return;
    const int rv = rcv[i];
    const int r = rv >> RANGE_BITS;
    const int s = i >> SLICE_BITS;
    const int pref = partial[(size_t)(r * NS + s) * RANGE + (rv & (RANGE - 1))];
    const int pos = rowptr[rv] + pref + pos_local[i];
    csr_src[pos] = snd[i];
}

// ---------------- fused MLP + W3 projection:
// p = rin * ( lrelu(lrelu(X@W1+b1)@W2+b2) @ W3 )   [N,40]
__global__ __launch_bounds__(256) void mlp_kernel(
    const float* __restrict__ X, const float* __restrict__ W1, const float* __restrict__ b1,
    const float* __restrict__ W2, const float* __restrict__ b2, const float* __restrict__ W3,
    const float* __restrict__ rin, float* __restrict__ p, int nN)
{
    __shared__ float W2s[64 * 64];
    __shared__ float Wc[16 * 64];
    __shared__ float Xs[16][68];
    __shared__ float H1s[64][68];

    const int t  = threadIdx.x;
    const int tx = t & 15;
    const int ty = t >> 4;
    const int row0 = blockIdx.x * 64;

    for (int i = t; i < 1024; i += 256)
        ((float4*)W2s)[i] = ((const float4*)W2)[i];

    const float4 bias1 = *(const float4*)&b1[4 * tx];
    const float4 bias2 = *(const float4*)&b2[4 * tx];

    float acc[4][4];
#pragma unroll
    for (int i = 0; i < 4; ++i)
#pragma unroll
        for (int j = 0; j < 4; ++j) acc[i][j] = 0.f;

    const int r  = t >> 2;
    const int kq = (t & 3) * 4;
    const int grow_ld = row0 + r;

    for (int kc = 0; kc < 8; ++kc) {
        float4 v = make_float4(0.f, 0.f, 0.f, 0.f);
        if (grow_ld < nN) v = *(const float4*)&X[(size_t)grow_ld * 128 + kc * 16 + kq];
        float4 w4 = ((const float4*)(W1 + kc * 1024))[t];
        __syncthreads();
        Xs[kq + 0][r] = v.x; Xs[kq + 1][r] = v.y; Xs[kq + 2][r] = v.z; Xs[kq + 3][r] = v.w;
        ((float4*)Wc)[t] = w4;
        __syncthreads();
#pragma unroll
        for (int k = 0; k < 16; ++k) {
            const float4 a = *(const float4*)&Xs[k][4 * ty];
            const float4 b = *(const float4*)&Wc[k * 64 + 4 * tx];
            acc[0][0] += a.x * b.x; acc[0][1] += a.x * b.y; acc[0][2] += a.x * b.z; acc[0][3] += a.x * b.w;
            acc[1][0] += a.y * b.x; acc[1][1] += a.y * b.y; acc[1][2] += a.y * b.z; acc[1][3] += a.y * b.w;
            acc[2][0] += a.z * b.x; acc[2][1] += a.z * b.y; acc[2][2] += a.z * b.z; acc[2][3] += a.z * b.w;
            acc[3][0] += a.w * b.x; acc[3][1] += a.w * b.y; acc[3][2] += a.w * b.z; acc[3][3] += a.w * b.w;
        }
    }

    __syncthreads();
#pragma unroll
    for (int i = 0; i < 4; ++i) {
        float h0 = lrelu(acc[i][0] + bias1.x);
        float h1 = lrelu(acc[i][1] + bias1.y);
        float h2 = lrelu(acc[i][2] + bias1.z);
        float h3 = lrelu(acc[i][3] + bias1.w);
        H1s[4 * tx + 0][4 * ty + i] = h0;
        H1s[4 * tx + 1][4 * ty + i] = h1;
        H1s[4 * tx + 2][4 * ty + i] = h2;
        H1s[4 * tx + 3][4 * ty + i] = h3;
    }
    __syncthreads();

#pragma unroll
    for (int i = 0; i < 4; ++i)
#pragma unroll
        for (int j = 0; j < 4; ++j) acc[i][j] = 0.f;

#pragma unroll 4
    for (int k = 0; k < 64; ++k) {
        const float4 a = *(const float4*)&H1s[k][4 * ty];
        const float4 b = *(const float4*)&W2s[k * 64 + 4 * tx];
        acc[0][0] += a.x * b.x; acc[0][1] += a.x * b.y; acc[0][2] += a.x * b.z; acc[0][3] += a.x * b.w;
        acc[1][0] += a.y * b.x; acc[1][1] += a.y * b.y; acc[1][2] += a.y * b.z; acc[1][3] += a.y * b.w;
        acc[2][0] += a.z * b.x; acc[2][1] += a.z * b.y; acc[2][2] += a.z * b.z; acc[2][3] += a.z * b.w;
        acc[3][0] += a.w * b.x; acc[3][1] += a.w * b.y; acc[3][2] += a.w * b.z; acc[3][3] += a.w * b.w;
    }

    __syncthreads();
#pragma unroll
    for (int i = 0; i < 4; ++i) {
        H1s[4 * ty + i][4 * tx + 0] = lrelu(acc[i][0] + bias2.x);
        H1s[4 * ty + i][4 * tx + 1] = lrelu(acc[i][1] + bias2.y);
        H1s[4 * ty + i][4 * tx + 2] = lrelu(acc[i][2] + bias2.z);
        H1s[4 * ty + i][4 * tx + 3] = lrelu(acc[i][3] + bias2.w);
    }
    for (int idx = t; idx < 640; idx += 256)
        ((float4*)W2s)[idx] = ((const float4*)W3)[idx];
    __syncthreads();

    const int row  = t >> 2;
    const int cseg = t & 3;
    float a10[10];
#pragma unroll
    for (int j = 0; j < 10; ++j) a10[j] = 0.f;
    for (int k = 0; k < 64; ++k) {
        const float a = H1s[row][k];
        const float* w = &W2s[k * 40 + cseg * 10];
#pragma unroll
        for (int j = 0; j < 10; ++j) a10[j] += a * w[j];
    }
    const int grow = row0 + row;
    if (grow < nN) {
        const float rs = rin[grow];
        float* pr = &p[(size_t)grow * 40 + cseg * 10];
#pragma unroll
        for (int m = 0; m < 5; ++m) {
            float2 st = make_float2(a10[2 * m] * rs, a10[2 * m + 1] * rs);
            ((float2*)pr)[m] = st;
        }
    }
}

// ---------------- agg1 (CSR gather): q = rin*rout * sum_{src} p[src]; c = rout * sum rin[src]
__global__ __launch_bounds__(256) void agg1_kernel(const float* __restrict__ p,
                                                   const int* __restrict__ csr_src,
                                                   const int* __restrict__ rowptr,
                                                   const float* __restrict__ rin,
                                                   const float* __restrict__ rout,
                                                   float* __restrict__ qbuf,
                                                   float* __restrict__ cbuf, int nN)
{
    const int gid = blockIdx.x * 256 + threadIdx.x;
    const int node = gid >> 2;
    const int q4 = gid & 3;
    if (node >= nN) return;
    const int beg = rowptr[node], end = rowptr[node + 1];
    const int jb0 = q4, jb1 = 4 + q4, jb2 = 8 + q4;
    const bool has2 = (q4 < 2);
    float4 a0 = make_float4(0, 0, 0, 0), a1 = a0, a2 = a0;
    float cs = 0.f;
    for (int e = beg; e < end; ++e) {
        const int src = csr_src[e];
        const float4* px = (const float4*)(p + (size_t)src * 40);
        a0 = add4(a0, px[jb0]);
        a1 = add4(a1, px[jb1]);
        if (has2) a2 = add4(a2, px[jb2]);
        if (q4 == 0) cs += rin[src];
    }
    const float sc = rin[node] * rout[node];
    float4* qr = (float4*)(qbuf + (size_t)node * 40);
    qr[jb0] = mul4(a0, sc);
    qr[jb1] = mul4(a1, sc);
    if (has2) qr[jb2] = mul4(a2, sc);
    if (q4 == 0) cbuf[node] = cs * rout[node];
}

// ---------------- agg2 + bias-term + softmax -> out ----------------
__global__ __launch_bounds__(256) void agg2_kernel(const float* __restrict__ qbuf,
                                                   const int* __restrict__ csr_src,
                                                   const int* __restrict__ rowptr,
                                                   const float* __restrict__ rout,
                                                   const float* __restrict__ cbuf,
                                                   const float* __restrict__ b3,
                                                   float* __restrict__ out, int nN)
{
    const int gid = blockIdx.x * 256 + threadIdx.x;
    const int node = gid >> 2;
    const int q4 = gid & 3;
    if (node >= nN) return;
    const int beg = rowptr[node], end = rowptr[node + 1];
    const int jb0 = q4, jb1 = 4 + q4, jb2 = 8 + q4;
    const bool has2 = (q4 < 2);
    float4 a0 = make_float4(0, 0, 0, 0), a1 = a0, a2 = a0;
    for (int e = beg; e < end; ++e) {
        const int src = csr_src[e];
        const float4* px = (const float4*)(qbuf + (size_t)src * 40);
        a0 = add4(a0, px[jb0]);
        a1 = add4(a1, px[jb1]);
        if (has2) a2 = add4(a2, px[jb2]);
    }
    const float ro = rout[node];
    const float c  = cbuf[node];
    const float4 b0 = ((const float4*)b3)[jb0];
    const float4 b1 = ((const float4*)b3)[jb1];
    float4 z0 = fma4(mul4(a0, ro), c, b0);
    float4 z1 = fma4(mul4(a1, ro), c, b1);
    float4 z2 = make_float4(0, 0, 0, 0);
    if (has2) {
        const float4 b2v = ((const float4*)b3)[jb2];
        z2 = fma4(mul4(a2, ro), c, b2v);
    }
    float m = fmaxf(fmaxf(z0.x, z0.y), fmaxf(z0.z, z0.w));
    m = fmaxf(m, fmaxf(fmaxf(z1.x, z1.y), fmaxf(z1.z, z1.w)));
    if (has2) m = fmaxf(m, fmaxf(fmaxf(z2.x, z2.y), fmaxf(z2.z, z2.w)));
    m = fmaxf(m, __shfl_xor(m, 1));
    m = fmaxf(m, __shfl_xor(m, 2));
    z0.x = __expf(z0.x - m); z0.y = __expf(z0.y - m); z0.z = __expf(z0.z - m); z0.w = __expf(z0.w - m);
    z1.x = __expf(z1.x - m); z1.y = __expf(z1.y - m); z1.z = __expf(z1.z - m); z1.w = __expf(z1.w - m);
    float s = z0.x + z0.y + z0.z + z0.w + z1.x + z1.y + z1.z + z1.w;
    if (has2) {
        z2.x = __expf(z2.x - m); z2.y = __expf(z2.y - m); z2.z = __expf(z2.z - m); z2.w = __expf(z2.w - m);
        s += z2.x + z2.y + z2.z + z2.w;
    }
    s += __shfl_xor(s, 1);
    s += __shfl_xor(s, 2);
    const float inv = 1.f / s;
    float4* orow = (float4*)(out + (size_t)node * 40);
    orow[jb0] = mul4(z0, inv);
    orow[jb1] = mul4(z1, inv);
    if (has2) orow[jb2] = mul4(z2, inv);
}

extern "C" void kernel_launch(void* const* d_in, const int* in_sizes, int n_in,
                              void* d_out, int out_size, void* d_ws, size_t ws_size,
                              hipStream_t stream)
{
    const float* nodes = (const float*)d_in[0];
    const int*   snd   = (const int*)d_in[1];
    const int*   rcv   = (const int*)d_in[2];
    const float* W1    = (const float*)d_in[3];
    const float* b1    = (const float*)d_in[4];
    const float* W2    = (const float*)d_in[5];
    const float* b2    = (const float*)d_in[6];
    const float* W3    = (const float*)d_in[7];
    const float* b3    = (const float*)d_in[8];

    const int nN = in_sizes[0] / 128;
    const int nE = in_sizes[1];
    const int NR = (nN + RANGE - 1) >> RANGE_BITS;   // 7 for N=100000
    const int NS = (nE + SLICE - 1) >> SLICE_BITS;   // 25 for E=1.6M

    // workspace layout (element offsets, 16B-aligned chunks)
    size_t off = 0;
    auto alloc = [&](size_t n) { size_t r = off; off += (n + 3) & ~(size_t)3; return r; };
    int*   dr_i    = (int*)d_ws + alloc(nN);
    int*   rowptr  = (int*)d_ws + alloc(nN + 1);
    int*   bsums   = (int*)d_ws + alloc(256);
    float* rin     = (float*)d_ws + alloc(nN);
    float* rout    = (float*)d_ws + alloc(nN);
    float* cbuf    = (float*)d_ws + alloc(nN);
    int*   csr_src = (int*)d_ws + alloc(nE);
    // union region: {partial + pos_local} (dead after fill) overlaps {pbuf + qbuf}
    const size_t psz = (size_t)2 * NR * NS * RANGE;
    size_t ubase = alloc(0);
    int*   partial   = (int*)d_ws + ubase;
    int*   pos_local = (int*)d_ws + ubase + psz;
    float* pbuf      = (float*)d_ws + ubase;
    float* qbuf      = (float*)d_ws + ubase + (size_t)nN * 40;

    const int nb1 = (nN + 1023) / 1024;   // <=256 required

    count_kernel<<<2 * NR * NS, 1024, 0, stream>>>(snd, rcv, partial, pos_local, nE, NR, NS);
    scanp_kernel<<<(NR * RANGE + 255) / 256, 256, 0, stream>>>(partial, dr_i, rin, rout, nN, NR, NS);
    scan1_kernel<<<nb1, 256, 0, stream>>>(dr_i, rowptr, bsums, nN);
    scan2_kernel<<<1, 256, 0, stream>>>(bsums, nb1);
    scan3_kernel<<<(nN + 255) / 256, 256, 0, stream>>>(rowptr, bsums, nN, nE);
    fill_kernel<<<(nE + 255) / 256, 256, 0, stream>>>(snd, rcv, pos_local, partial, rowptr, csr_src, nE, NS);
    mlp_kernel<<<(nN + 63) / 64, 256, 0, stream>>>(nodes, W1, b1, W2, b2, W3, rin, pbuf, nN);
    agg1_kernel<<<((size_t)nN * 4 + 255) / 256, 256, 0, stream>>>(pbuf, csr_src, rowptr, rin, rout, qbuf, cbuf, nN);
    agg2_kernel<<<((size_t)nN * 4 + 255) / 256, 256, 0, stream>>>(qbuf, csr_src, rowptr, rout, cbuf, b3, (float*)d_out, nN);
}

// Round 4
// 250.436 us; speedup vs baseline: 10.4665x; 1.1664x over previous
//
#include <hip/hip_runtime.h>
#include <hip/hip_fp16.h>

#define NEG_SLOPE 0.01f
#define RANGE_BITS 14
#define RANGE (1 << RANGE_BITS)     // 16384 nodes per histogram range (64 KB LDS)
#define SLICE_BITS 16
#define SLICE (1 << SLICE_BITS)     // 65536 edges per slice

__device__ __forceinline__ float lrelu(float x) { return x > 0.f ? x : NEG_SLOPE * x; }

__device__ __forceinline__ unsigned pack2(float a, float b) {
    __half2 h = __floats2half2_rn(a, b);
    return *reinterpret_cast<unsigned*>(&h);
}
__device__ __forceinline__ float2 unpack2(unsigned u) {
    __half2 h = *reinterpret_cast<__half2*>(&u);
    return __half22float2(h);
}

// ---------------- pass A: per-(array,range,slice) LDS histogram ----------------
__global__ __launch_bounds__(1024) void count_kernel(
    const int* __restrict__ snd, const int* __restrict__ rcv,
    int* __restrict__ partial, int* __restrict__ pos_local,
    int nE, int NR, int NS)
{
    __shared__ int hist[RANGE];
    const int b = blockIdx.x;
    const int a = b / (NR * NS);
    const int rem = b - a * NR * NS;
    const int r = rem / NS;
    const int s = rem - r * NS;
    const int t = threadIdx.x;
    for (int k = t; k < RANGE; k += 1024) hist[k] = 0;
    __syncthreads();
    const int base = r << RANGE_BITS;
    const int lo = s << SLICE_BITS;
    const int hi = min(lo + SLICE, nE);
    if (a == 0) {
        for (int i = lo + t; i < hi; i += 1024) {
            const int v = rcv[i];
            const unsigned d = (unsigned)(v - base);
            if (d < (unsigned)RANGE) {
                const int lp = atomicAdd(&hist[d], 1);
                pos_local[i] = lp;
            }
        }
    } else {
        for (int i = lo + t; i < hi; i += 1024) {
            const int v = snd[i];
            const unsigned d = (unsigned)(v - base);
            if (d < (unsigned)RANGE) atomicAdd(&hist[d], 1);
        }
    }
    __syncthreads();
    int* dst = partial + (size_t)((a * NR + r) * NS + s) * RANGE;
    for (int k = t; k < RANGE; k += 1024) dst[k] = hist[k];
}

// ---------------- pass B: scan rcv partials over slices, degrees, rin/rout ----------------
__global__ __launch_bounds__(256) void scanp_kernel(
    int* __restrict__ partial,
    int* __restrict__ dr_i,
    float* __restrict__ rin, float* __restrict__ rout,
    int nN, int NR, int NS)
{
    const int gid = blockIdx.x * 256 + threadIdx.x;
    if (gid >= (NR << RANGE_BITS)) return;
    const int r = gid >> RANGE_BITS;
    const int node = gid & (RANGE - 1);
    int* prcv = partial + (size_t)(r * NS) * RANGE + node;
    int run = 0;
    for (int s = 0; s < NS; ++s) {
        int* p = prcv + (size_t)s * RANGE;
        const int c = *p;
        *p = run;
        run += c;
    }
    const int* psnd = partial + (size_t)((NR + r) * NS) * RANGE + node;
    int tot = 0;
    for (int s = 0; s < NS; ++s) tot += psnd[(size_t)s * RANGE];
    if (gid < nN) {
        dr_i[gid] = run;
        rout[gid] = rsqrtf(fmaxf((float)run, 1.f));
        rin[gid]  = rsqrtf(fmaxf((float)tot, 1.f));
    }
}

// ---------------- scan stage 1 ----------------
__global__ __launch_bounds__(256) void scan1_kernel(const int* __restrict__ cnt,
                                                    int* __restrict__ rowptr,
                                                    int* __restrict__ bsums, int n)
{
    __shared__ int sd[256];
    const int t = threadIdx.x;
    const int base = blockIdx.x * 1024 + t * 4;
    int v0 = (base + 0 < n) ? cnt[base + 0] : 0;
    int v1 = (base + 1 < n) ? cnt[base + 1] : 0;
    int v2 = (base + 2 < n) ? cnt[base + 2] : 0;
    int v3 = (base + 3 < n) ? cnt[base + 3] : 0;
    const int p1 = v0, p2 = v0 + v1, p3 = v0 + v1 + v2;
    const int tot = p3 + v3;
    sd[t] = tot;
    __syncthreads();
    for (int off = 1; off < 256; off <<= 1) {
        int y = (t >= off) ? sd[t - off] : 0;
        __syncthreads();
        sd[t] += y;
        __syncthreads();
    }
    const int excl = sd[t] - tot;
    if (base + 0 < n) rowptr[base + 0] = excl;
    if (base + 1 < n) rowptr[base + 1] = excl + p1;
    if (base + 2 < n) rowptr[base + 2] = excl + p2;
    if (base + 3 < n) rowptr[base + 3] = excl + p3;
    if (t == 255) bsums[blockIdx.x] = sd[255];
}

// ---------------- scan stage 2 ----------------
__global__ __launch_bounds__(256) void scan2_kernel(int* __restrict__ bsums, int nb)
{
    __shared__ int sd[256];
    const int t = threadIdx.x;
    const int v = (t < nb) ? bsums[t] : 0;
    sd[t] = v;
    __syncthreads();
    for (int off = 1; off < 256; off <<= 1) {
        int y = (t >= off) ? sd[t - off] : 0;
        __syncthreads();
        sd[t] += y;
        __syncthreads();
    }
    if (t < nb) bsums[t] = sd[t] - v;
}

// ---------------- scan stage 3 ----------------
__global__ __launch_bounds__(256) void scan3_kernel(int* __restrict__ rowptr,
                                                    const int* __restrict__ bsums,
                                                    int n, int nE)
{
    const int gid = blockIdx.x * 256 + threadIdx.x;
    if (gid < n) rowptr[gid] += bsums[gid >> 10];
    if (gid == 0) rowptr[n] = nE;
}

// ---------------- pass C: atomic-free CSR fill ----------------
__global__ __launch_bounds__(256) void fill_kernel(
    const int* __restrict__ snd, const int* __restrict__ rcv,
    const int* __restrict__ pos_local, const int* __restrict__ partial,
    const int* __restrict__ rowptr, int* __restrict__ csr_src,
    int nE, int NS)
{
    const int i = blockIdx.x * 256 + threadIdx.x;
    if (i >= nE) return;
    const int rv = rcv[i];
    const int r = rv >> RANGE_BITS;
    const int s = i >> SLICE_BITS;
    const int pref = partial[(size_t)(r * NS + s) * RANGE + (rv & (RANGE - 1))];
    const int pos = rowptr[rv] + pref + pos_local[i];
    csr_src[pos] = snd[i];
}

// ---------------- fused MLP + W3 projection (fp16 output):
// p = fp16( rin * ( lrelu(lrelu(X@W1+b1)@W2+b2) @ W3 ) )   [N,40]
__global__ __launch_bounds__(256) void mlp_kernel(
    const float* __restrict__ X, const float* __restrict__ W1, const float* __restrict__ b1,
    const float* __restrict__ W2, const float* __restrict__ b2, const float* __restrict__ W3,
    const float* __restrict__ rin, __half* __restrict__ p, int nN)
{
    __shared__ float W2s[64 * 64];
    __shared__ float Wc[16 * 64];
    __shared__ float Xs[16][68];
    __shared__ float H1s[64][68];

    const int t  = threadIdx.x;
    const int tx = t & 15;
    const int ty = t >> 4;
    const int row0 = blockIdx.x * 64;

    for (int i = t; i < 1024; i += 256)
        ((float4*)W2s)[i] = ((const float4*)W2)[i];

    const float4 bias1 = *(const float4*)&b1[4 * tx];
    const float4 bias2 = *(const float4*)&b2[4 * tx];

    float acc[4][4];
#pragma unroll
    for (int i = 0; i < 4; ++i)
#pragma unroll
        for (int j = 0; j < 4; ++j) acc[i][j] = 0.f;

    const int r  = t >> 2;
    const int kq = (t & 3) * 4;
    const int grow_ld = row0 + r;

    for (int kc = 0; kc < 8; ++kc) {
        float4 v = make_float4(0.f, 0.f, 0.f, 0.f);
        if (grow_ld < nN) v = *(const float4*)&X[(size_t)grow_ld * 128 + kc * 16 + kq];
        float4 w4 = ((const float4*)(W1 + kc * 1024))[t];
        __syncthreads();
        Xs[kq + 0][r] = v.x; Xs[kq + 1][r] = v.y; Xs[kq + 2][r] = v.z; Xs[kq + 3][r] = v.w;
        ((float4*)Wc)[t] = w4;
        __syncthreads();
#pragma unroll
        for (int k = 0; k < 16; ++k) {
            const float4 a = *(const float4*)&Xs[k][4 * ty];
            const float4 b = *(const float4*)&Wc[k * 64 + 4 * tx];
            acc[0][0] += a.x * b.x; acc[0][1] += a.x * b.y; acc[0][2] += a.x * b.z; acc[0][3] += a.x * b.w;
            acc[1][0] += a.y * b.x; acc[1][1] += a.y * b.y; acc[1][2] += a.y * b.z; acc[1][3] += a.y * b.w;
            acc[2][0] += a.z * b.x; acc[2][1] += a.z * b.y; acc[2][2] += a.z * b.z; acc[2][3] += a.z * b.w;
            acc[3][0] += a.w * b.x; acc[3][1] += a.w * b.y; acc[3][2] += a.w * b.z; acc[3][3] += a.w * b.w;
        }
    }

    __syncthreads();
#pragma unroll
    for (int i = 0; i < 4; ++i) {
        float h0 = lrelu(acc[i][0] + bias1.x);
        float h1 = lrelu(acc[i][1] + bias1.y);
        float h2 = lrelu(acc[i][2] + bias1.z);
        float h3 = lrelu(acc[i][3] + bias1.w);
        H1s[4 * tx + 0][4 * ty + i] = h0;
        H1s[4 * tx + 1][4 * ty + i] = h1;
        H1s[4 * tx + 2][4 * ty + i] = h2;
        H1s[4 * tx + 3][4 * ty + i] = h3;
    }
    __syncthreads();

#pragma unroll
    for (int i = 0; i < 4; ++i)
#pragma unroll
        for (int j = 0; j < 4; ++j) acc[i][j] = 0.f;

#pragma unroll 4
    for (int k = 0; k < 64; ++k) {
        const float4 a = *(const float4*)&H1s[k][4 * ty];
        const float4 b = *(const float4*)&W2s[k * 64 + 4 * tx];
        acc[0][0] += a.x * b.x; acc[0][1] += a.x * b.y; acc[0][2] += a.x * b.z; acc[0][3] += a.x * b.w;
        acc[1][0] += a.y * b.x; acc[1][1] += a.y * b.y; acc[1][2] += a.y * b.z; acc[1][3] += a.y * b.w;
        acc[2][0] += a.z * b.x; acc[2][1] += a.z * b.y; acc[2][2] += a.z * b.z; acc[2][3] += a.z * b.w;
        acc[3][0] += a.w * b.x; acc[3][1] += a.w * b.y; acc[3][2] += a.w * b.z; acc[3][3] += a.w * b.w;
    }

    __syncthreads();
#pragma unroll
    for (int i = 0; i < 4; ++i) {
        H1s[4 * ty + i][4 * tx + 0] = lrelu(acc[i][0] + bias2.x);
        H1s[4 * ty + i][4 * tx + 1] = lrelu(acc[i][1] + bias2.y);
        H1s[4 * ty + i][4 * tx + 2] = lrelu(acc[i][2] + bias2.z);
        H1s[4 * ty + i][4 * tx + 3] = lrelu(acc[i][3] + bias2.w);
    }
    for (int idx = t; idx < 640; idx += 256)
        ((float4*)W2s)[idx] = ((const float4*)W3)[idx];
    __syncthreads();

    const int row  = t >> 2;
    const int cseg = t & 3;
    float a10[10];
#pragma unroll
    for (int j = 0; j < 10; ++j) a10[j] = 0.f;
    for (int k = 0; k < 64; ++k) {
        const float a = H1s[row][k];
        const float* w = &W2s[k * 40 + cseg * 10];
#pragma unroll
        for (int j = 0; j < 10; ++j) a10[j] += a * w[j];
    }
    const int grow = row0 + row;
    if (grow < nN) {
        const float rs = rin[grow];
        unsigned* pr = (unsigned*)(p + (size_t)grow * 40 + cseg * 10);
#pragma unroll
        for (int m = 0; m < 5; ++m)
            pr[m] = pack2(a10[2 * m] * rs, a10[2 * m + 1] * rs);
    }
}

// ---------------- agg1 (fp16 CSR gather): q = rin*rout * sum p[src]; c = rout * sum rin[src]
__global__ __launch_bounds__(256) void agg1_kernel(const __half* __restrict__ p,
                                                   const int* __restrict__ csr_src,
                                                   const int* __restrict__ rowptr,
                                                   const float* __restrict__ rin,
                                                   const float* __restrict__ rout,
                                                   __half* __restrict__ qbuf,
                                                   float* __restrict__ cbuf, int nN)
{
    const int gid = blockIdx.x * 256 + threadIdx.x;
    const int node = gid >> 2;
    const int q4 = gid & 3;
    if (node >= nN) return;
    const int beg = rowptr[node], end = rowptr[node + 1];
    const bool has2 = (q4 == 1);       // lane 1 also owns chunk 4; lane 0 owns rin-sum
    float a[16];
#pragma unroll
    for (int j = 0; j < 16; ++j) a[j] = 0.f;
    float cs = 0.f;
    for (int e = beg; e < end; ++e) {
        const int src = csr_src[e];
        const uint4* row = (const uint4*)(p + (size_t)src * 40);
        const uint4 u = row[q4];
        float2 f;
        f = unpack2(u.x); a[0] += f.x; a[1] += f.y;
        f = unpack2(u.y); a[2] += f.x; a[3] += f.y;
        f = unpack2(u.z); a[4] += f.x; a[5] += f.y;
        f = unpack2(u.w); a[6] += f.x; a[7] += f.y;
        if (has2) {
            const uint4 v = row[4];
            f = unpack2(v.x); a[8]  += f.x; a[9]  += f.y;
            f = unpack2(v.y); a[10] += f.x; a[11] += f.y;
            f = unpack2(v.z); a[12] += f.x; a[13] += f.y;
            f = unpack2(v.w); a[14] += f.x; a[15] += f.y;
        }
        if (q4 == 0) cs += rin[src];
    }
    const float sc = rin[node] * rout[node];
    uint4 o;
    o.x = pack2(a[0] * sc, a[1] * sc);
    o.y = pack2(a[2] * sc, a[3] * sc);
    o.z = pack2(a[4] * sc, a[5] * sc);
    o.w = pack2(a[6] * sc, a[7] * sc);
    uint4* qr = (uint4*)(qbuf + (size_t)node * 40);
    qr[q4] = o;
    if (has2) {
        uint4 o2;
        o2.x = pack2(a[8]  * sc, a[9]  * sc);
        o2.y = pack2(a[10] * sc, a[11] * sc);
        o2.z = pack2(a[12] * sc, a[13] * sc);
        o2.w = pack2(a[14] * sc, a[15] * sc);
        qr[4] = o2;
    }
    if (q4 == 0) cbuf[node] = cs * rout[node];
}

// ---------------- agg2 + bias-term + softmax -> out (f32) ----------------
__global__ __launch_bounds__(256) void agg2_kernel(const __half* __restrict__ qbuf,
                                                   const int* __restrict__ csr_src,
                                                   const int* __restrict__ rowptr,
                                                   const float* __restrict__ rout,
                                                   const float* __restrict__ cbuf,
                                                   const float* __restrict__ b3,
                                                   float* __restrict__ out, int nN)
{
    const int gid = blockIdx.x * 256 + threadIdx.x;
    const int node = gid >> 2;
    const int q4 = gid & 3;
    if (node >= nN) return;
    const int beg = rowptr[node], end = rowptr[node + 1];
    const bool has2 = (q4 == 1);
    float a[16];
#pragma unroll
    for (int j = 0; j < 16; ++j) a[j] = 0.f;
    for (int e = beg; e < end; ++e) {
        const int src = csr_src[e];
        const uint4* row = (const uint4*)(qbuf + (size_t)src * 40);
        const uint4 u = row[q4];
        float2 f;
        f = unpack2(u.x); a[0] += f.x; a[1] += f.y;
        f = unpack2(u.y); a[2] += f.x; a[3] += f.y;
        f = unpack2(u.z); a[4] += f.x; a[5] += f.y;
        f = unpack2(u.w); a[6] += f.x; a[7] += f.y;
        if (has2) {
            const uint4 v = row[4];
            f = unpack2(v.x); a[8]  += f.x; a[9]  += f.y;
            f = unpack2(v.y); a[10] += f.x; a[11] += f.y;
            f = unpack2(v.z); a[12] += f.x; a[13] += f.y;
            f = unpack2(v.w); a[14] += f.x; a[15] += f.y;
        }
    }
    const float ro = rout[node];
    const float c  = cbuf[node];
    float z[16];
#pragma unroll
    for (int j = 0; j < 8; ++j) z[j] = ro * a[j] + c * b3[q4 * 8 + j];
    if (has2) {
#pragma unroll
        for (int j = 0; j < 8; ++j) z[8 + j] = ro * a[8 + j] + c * b3[32 + j];
    }
    float m = z[0];
#pragma unroll
    for (int j = 1; j < 8; ++j) m = fmaxf(m, z[j]);
    if (has2) {
#pragma unroll
        for (int j = 8; j < 16; ++j) m = fmaxf(m, z[j]);
    }
    m = fmaxf(m, __shfl_xor(m, 1));
    m = fmaxf(m, __shfl_xor(m, 2));
    float s = 0.f;
#pragma unroll
    for (int j = 0; j < 8; ++j) { z[j] = __expf(z[j] - m); s += z[j]; }
    if (has2) {
#pragma unroll
        for (int j = 8; j < 16; ++j) { z[j] = __expf(z[j] - m); s += z[j]; }
    }
    s += __shfl_xor(s, 1);
    s += __shfl_xor(s, 2);
    const float inv = 1.f / s;
    float4* orow = (float4*)(out + (size_t)node * 40);
    orow[q4 * 2 + 0] = make_float4(z[0] * inv, z[1] * inv, z[2] * inv, z[3] * inv);
    orow[q4 * 2 + 1] = make_float4(z[4] * inv, z[5] * inv, z[6] * inv, z[7] * inv);
    if (has2) {
        orow[8] = make_float4(z[8]  * inv, z[9]  * inv, z[10] * inv, z[11] * inv);
        orow[9] = make_float4(z[12] * inv, z[13] * inv, z[14] * inv, z[15] * inv);
    }
}

extern "C" void kernel_launch(void* const* d_in, const int* in_sizes, int n_in,
                              void* d_out, int out_size, void* d_ws, size_t ws_size,
                              hipStream_t stream)
{
    const float* nodes = (const float*)d_in[0];
    const int*   snd   = (const int*)d_in[1];
    const int*   rcv   = (const int*)d_in[2];
    const float* W1    = (const float*)d_in[3];
    const float* b1    = (const float*)d_in[4];
    const float* W2    = (const float*)d_in[5];
    const float* b2    = (const float*)d_in[6];
    const float* W3    = (const float*)d_in[7];
    const float* b3    = (const float*)d_in[8];

    const int nN = in_sizes[0] / 128;
    const int nE = in_sizes[1];
    const int NR = (nN + RANGE - 1) >> RANGE_BITS;   // 7 for N=100000
    const int NS = (nE + SLICE - 1) >> SLICE_BITS;   // 25 for E=1.6M

    size_t off = 0;
    auto alloc = [&](size_t n) { size_t r = off; off += (n + 3) & ~(size_t)3; return r; };
    int*   dr_i    = (int*)d_ws + alloc(nN);
    int*   rowptr  = (int*)d_ws + alloc(nN + 1);
    int*   bsums   = (int*)d_ws + alloc(256);
    float* rin     = (float*)d_ws + alloc(nN);
    float* rout    = (float*)d_ws + alloc(nN);
    float* cbuf    = (float*)d_ws + alloc(nN);
    int*   csr_src = (int*)d_ws + alloc(nE);
    // union region: {partial + pos_local} (dead after fill) overlaps {pbuf + qbuf} (fp16)
    const size_t psz = (size_t)2 * NR * NS * RANGE;
    size_t ubase = alloc(0);
    int*    partial   = (int*)d_ws + ubase;
    int*    pos_local = (int*)d_ws + ubase + psz;
    __half* pbuf      = (__half*)((int*)d_ws + ubase);
    __half* qbuf      = pbuf + (size_t)nN * 40;     // byte offset nN*80, 16B-aligned

    const int nb1 = (nN + 1023) / 1024;

    count_kernel<<<2 * NR * NS, 1024, 0, stream>>>(snd, rcv, partial, pos_local, nE, NR, NS);
    scanp_kernel<<<(NR * RANGE + 255) / 256, 256, 0, stream>>>(partial, dr_i, rin, rout, nN, NR, NS);
    scan1_kernel<<<nb1, 256, 0, stream>>>(dr_i, rowptr, bsums, nN);
    scan2_kernel<<<1, 256, 0, stream>>>(bsums, nb1);
    scan3_kernel<<<(nN + 255) / 256, 256, 0, stream>>>(rowptr, bsums, nN, nE);
    fill_kernel<<<(nE + 255) / 256, 256, 0, stream>>>(snd, rcv, pos_local, partial, rowptr, csr_src, nE, NS);
    mlp_kernel<<<(nN + 63) / 64, 256, 0, stream>>>(nodes, W1, b1, W2, b2, W3, rin, pbuf, nN);
    agg1_kernel<<<((size_t)nN * 4 + 255) / 256, 256, 0, stream>>>(pbuf, csr_src, rowptr, rin, rout, qbuf, cbuf, nN);
    agg2_kernel<<<((size_t)nN * 4 + 255) / 256, 256, 0, stream>>>(qbuf, csr_src, rowptr, rout, cbuf, b3, (float*)d_out, nN);
}